// Round 12
// baseline (15.432 us; speedup 1.0000x reference)
//
#include <hip/hip_runtime.h>

#define BATCH 4
#define N_CH 3
#define NUM_CLASSES 20
#define IMG_H 512
#define IMG_W 512
#define MAX_BOXES 50
#define NSLOTS (BATCH * MAX_BOXES)       // 200
#define PARTS 32                         // blocks per box slot (was 16)
#define NXCD 8
#define SLOTS_PER_XCD (NSLOTS / NXCD)    // 25
#define BLOCK 256
#define TOTAL_BLOCKS (NSLOTS * PARTS)    // 6400

// Block d -> (slot, part) with XCD affinity: hardware maps xcd = d % 8, so
// slot = (d%8)*25 + (d/8)/32, part = (d/8)%32 puts all 32 parts of a slot on
// ONE XCD -> the box's yf/im rows are reused out of that XCD's 4MB L2
// (~200cyc) instead of L3 (~400-500cyc). Latency-bound kernel -> direct win.
// Raw partial overwritten to ws[slot*PARTS+part] (no zero-init, no atomics).
__global__ __launch_bounds__(BLOCK)
void box_err_kernel(const float* __restrict__ y_fcn,
                    const float* __restrict__ im_data,
                    const int*   __restrict__ gt_boxes,
                    const int*   __restrict__ num_boxes,
                    float*       __restrict__ ws_part) {
    const int d    = (int)blockIdx.x;
    const int r    = d & (NXCD - 1);          // xcd
    const int q    = d >> 3;                  // 0..799
    const int slot = r * SLOTS_PER_XCD + (q >> 5);
    const int part = q & (PARTS - 1);
    const int b    = slot / MAX_BOXES;
    const int box  = slot % MAX_BOXES;
    const int tid  = (int)threadIdx.x;

    const int* g  = gt_boxes + slot * 5;
    const int x1 = g[0], y1 = g[1], x2 = g[2], y2 = g[3], cls = g[4];
    const int bh = y2 - y1;
    const int c0 = x1 & ~3;                    // 16B-aligned chunk start
    const int n4 = (x2 - c0 + 3) >> 2;         // float4 chunks per row

    const int nrows = (part < bh) ? ((bh - part + PARTS - 1) / PARTS) : 0;
    const int vmax  = (box < num_boxes[b]) ? nrows * n4 : 0;

    const int plane = IMG_H * IMG_W;
    const float* im = im_data + (size_t)b * N_CH * plane;
    const float* yf = y_fcn + ((size_t)b * NUM_CLASSES + cls) * (size_t)(N_CH * plane);

    float s = 0.0f;
    for (int v = tid; v < vmax; v += BLOCK) {
        const int rl  = v / n4;                // row index within this part
        const int ic  = v - rl * n4;           // chunk index within row
        const int row = y1 + part + rl * PARTS;
        const int cc  = c0 + (ic << 2);
        const int base = row * IMG_W + cc;     // float index, 16B aligned
        const float m0 = (cc + 0 >= x1 && cc + 0 < x2) ? 1.0f : 0.0f;
        const float m1 = (cc + 1 >= x1 && cc + 1 < x2) ? 1.0f : 0.0f;
        const float m2 = (cc + 2 >= x1 && cc + 2 < x2) ? 1.0f : 0.0f;
        const float m3 = (cc + 3 >= x1 && cc + 3 < x2) ? 1.0f : 0.0f;
        #pragma unroll
        for (int nn = 0; nn < N_CH; ++nn) {
            const float4 a = *(const float4*)(im + nn * plane + base);
            const float4 q4 = *(const float4*)(yf + nn * plane + base);
            float dd;
            dd = (a.x - q4.x) * m0; s = fmaf(dd, dd, s);
            dd = (a.y - q4.y) * m1; s = fmaf(dd, dd, s);
            dd = (a.z - q4.z) * m2; s = fmaf(dd, dd, s);
            dd = (a.w - q4.w) * m3; s = fmaf(dd, dd, s);
        }
    }

    #pragma unroll
    for (int off = 32; off > 0; off >>= 1)
        s += __shfl_down(s, off, 64);

    __shared__ float red[BLOCK / 64];
    if ((tid & 63) == 0) red[tid >> 6] = s;
    __syncthreads();
    if (tid == 0)
        ws_part[slot * PARTS + part] = red[0] + red[1] + red[2] + red[3];
}

// One block: slot t sums its 32 contiguous partials, divides by (3*area),
// masks invalid slots, reduces, divides by sum(num_boxes).
__global__ __launch_bounds__(BLOCK)
void finalize_kernel(const float* __restrict__ ws_part,
                     const int*   __restrict__ gt_boxes,
                     const int*   __restrict__ num_boxes,
                     float*       __restrict__ out) {
    const int t = (int)threadIdx.x;
    float e = 0.0f;
    if (t < NSLOTS) {
        const int b   = t / MAX_BOXES;
        const int box = t % MAX_BOXES;
        if (box < num_boxes[b]) {
            const float4* p = (const float4*)(ws_part + t * PARTS);
            float sum = 0.0f;
            #pragma unroll
            for (int k = 0; k < PARTS / 4; ++k) {
                const float4 s4 = p[k];
                sum += (s4.x + s4.y) + (s4.z + s4.w);
            }
            const int* g = gt_boxes + t * 5;
            const int area = (g[2] - g[0]) * (g[3] - g[1]);
            e = sum / (float)(N_CH * max(area, 1));
        }
    }
    #pragma unroll
    for (int off = 32; off > 0; off >>= 1)
        e += __shfl_down(e, off, 64);

    __shared__ float red[BLOCK / 64];
    if ((t & 63) == 0) red[t >> 6] = e;
    __syncthreads();
    if (t == 0) {
        int nb = 0;
        #pragma unroll
        for (int bb = 0; bb < BATCH; ++bb) nb += num_boxes[bb];
        out[0] = (red[0] + red[1] + red[2] + red[3]) / (float)nb;
    }
}

extern "C" void kernel_launch(void* const* d_in, const int* in_sizes, int n_in,
                              void* d_out, int out_size, void* d_ws, size_t ws_size,
                              hipStream_t stream) {
    const float* y_fcn     = (const float*)d_in[0];
    const float* im_data   = (const float*)d_in[1];
    // d_in[2] = im_info (unused)
    const int*   gt_boxes  = (const int*)d_in[3];
    const int*   num_boxes = (const int*)d_in[4];
    float* out     = (float*)d_out;
    float* ws_part = (float*)d_ws;         // TOTAL_BLOCKS floats

    box_err_kernel<<<TOTAL_BLOCKS, BLOCK, 0, stream>>>(
        y_fcn, im_data, gt_boxes, num_boxes, ws_part);

    finalize_kernel<<<1, BLOCK, 0, stream>>>(ws_part, gt_boxes, num_boxes, out);
}